// Round 2
// 92.906 us; speedup vs baseline: 1.0118x; 1.0118x over previous
//
#include <hip/hip_runtime.h>

// S4D real: y[l,c] = sum_s w[c,s] * h_s[l],  h_s[l] = x[l,c] + r[c,s]*h_s[l-1]
//
// R7: plain 3-dispatch blocked scan (cooperative launch removed — R6's
// grid.sync cooperative kernel killed the MI355X container twice; graph
// capture + cooperative co-residency is not trustworthy in this harness).
//   K1 k_local : per-chunk scan, zero carry-in, params computed in-register
//                (k_params kernel eliminated) -> chunk-end states
//   K2 k_comb  : chunk-end -> chunk carry-IN. NJ=4 threads per (s,c) pair,
//                group aggregates exchanged via LDS (one wave per group:
//                coalesced 256B loads, 4x the waves of the old serial walk)
//   K3 k_scan  : seeded re-scan + y = sum_s w*h, params in-register
// T=64 (NC=64): halves carry traffic vs T=32; total scan FMA work is
// T-invariant. 512 blocks = 2 blocks/CU, 2 waves/SIMD.

namespace {

constexpr int L_ = 4096;
constexpr int CH_ = 512;
constexpr int S_ = 64;
constexpr float DT = 1.0f / 4096.0f;
constexpr int SC = S_ * CH_;   // 32768 (s,c) pairs
constexpr int SG = 16;         // states per thread (S_ / 4 waves)
constexpr int T_ = 64;         // chunk length
constexpr int NC_ = L_ / T_;   // 64 chunks
constexpr int GJ = 16;         // chunks per combine thread
constexpr int NJ = NC_ / GJ;   // 4 combine groups per (s,c)

// Compute r (and optionally w) for states [s0, s0+16) of channel c.
__device__ __forceinline__ void params16(const float* __restrict__ la,
                                         const float* __restrict__ Bg,
                                         const float* __restrict__ Cg,
                                         int c, int s0, float* r, float* w) {
  const float4* lap = reinterpret_cast<const float4*>(la + c * S_ + s0);
  if (w == nullptr) {
#pragma unroll
    for (int q = 0; q < 4; ++q) {
      const float4 v = lap[q];
      const float a[4] = {v.x, v.y, v.z, v.w};
#pragma unroll
      for (int t = 0; t < 4; ++t) {
        const float A = -expf(a[t]);
        r[q * 4 + t] = expf(A * DT);
      }
    }
  } else {
    const float4* bp = reinterpret_cast<const float4*>(Bg + c * S_ + s0);
    const float4* cp = reinterpret_cast<const float4*>(Cg + c * S_ + s0);
#pragma unroll
    for (int q = 0; q < 4; ++q) {
      const float4 v = lap[q], bb = bp[q], cc = cp[q];
      const float a[4] = {v.x, v.y, v.z, v.w};
      const float bv[4] = {bb.x, bb.y, bb.z, bb.w};
      const float cv[4] = {cc.x, cc.y, cc.z, cc.w};
#pragma unroll
      for (int t = 0; t < 4; ++t) {
        const float A = -expf(a[t]);
        const float rr = expf(A * DT);
        r[q * 4 + t] = rr;
        w[q * 4 + t] = cv[t] * ((rr - 1.0f) * bv[t] / A);
      }
    }
  }
}

// ---------------- K1: local chunk-end states (zero carry-in) ----------------
// grid = NC*8, block = 256 (4 waves). wave g: states [16g,16g+16), lane: c.
template <int T>
__global__ __launch_bounds__(256) void k_local(const float* __restrict__ x,
                                               const float* __restrict__ la,
                                               float* __restrict__ carry) {
  const int lane = threadIdx.x & 63;
  const int g = threadIdx.x >> 6;
  const int k = blockIdx.x >> 3;
  const int c = ((blockIdx.x & 7) << 6) + lane;
  const int s0 = g * SG;

  float r[SG], h[SG];
  params16(la, nullptr, nullptr, c, s0, r, nullptr);
#pragma unroll
  for (int i = 0; i < SG; ++i) h[i] = 0.0f;

  const float* xp = x + (size_t)k * T * CH_ + c;
#pragma unroll 8
  for (int l = 0; l < T; ++l) {
    const float xv = xp[l * CH_];
#pragma unroll
    for (int i = 0; i < SG; ++i) h[i] = fmaf(r[i], h[i], xv);
  }

  float* cw = carry + (size_t)k * SC + s0 * CH_ + c;
#pragma unroll
  for (int i = 0; i < SG; ++i) cw[i * CH_] = h[i];
}

// ---------------- K2: chunk ends -> chunk carry-ins (in place) --------------
// Block: 64 pids x NJ groups (wave j owns chunks [GJ*j, GJ*j+GJ)).
// Loads/stores coalesced 256B per wave; group prefix via LDS.
__global__ __launch_bounds__(256) void k_comb(const float* __restrict__ la,
                                              float* __restrict__ carry) {
  __shared__ float aggs[NJ][64];
  const int p = threadIdx.x & 63;
  const int j = threadIdx.x >> 6;            // 0..NJ-1, wave-uniform
  const int pid = (blockIdx.x << 6) + p;     // s*CH + c
  const int s = pid >> 9;
  const int c = pid & (CH_ - 1);

  const float A = -expf(la[c * S_ + s]);
  const float rT = expf(A * (DT * (float)T_));  // r^T
  float rTG = rT * rT;                           // rT^2
  rTG *= rTG;                                    // ^4
  rTG *= rTG;                                    // ^8
  rTG *= rTG;                                    // ^16 = rT^GJ

  float v[GJ];
#pragma unroll
  for (int m = 0; m < GJ; ++m) v[m] = carry[(size_t)(j * GJ + m) * SC + pid];

  float agg = 0.0f;
#pragma unroll
  for (int m = 0; m < GJ; ++m) agg = fmaf(rT, agg, v[m]);
  aggs[j][p] = agg;
  __syncthreads();

  float G = 0.0f;  // carry-in of group j
  for (int j2 = 0; j2 < j; ++j2) G = fmaf(rTG, G, aggs[j2][p]);

  float st = G;
#pragma unroll
  for (int m = 0; m < GJ; ++m) {
    carry[(size_t)(j * GJ + m) * SC + pid] = st;  // carry-IN of chunk GJ*j+m
    st = fmaf(rT, st, v[m]);
  }
}

// ---------------- K3: seeded re-scan + output -------------------------------
template <int T, bool USE_CARRY>
__global__ __launch_bounds__(256) void k_scan(const float* __restrict__ x,
                                              const float* __restrict__ la,
                                              const float* __restrict__ Bg,
                                              const float* __restrict__ Cg,
                                              const float* __restrict__ carry,
                                              float* __restrict__ y) {
  __shared__ float lds[4][8][64];  // [s-group][j][lane]

  const int lane = threadIdx.x & 63;
  const int g = threadIdx.x >> 6;
  const int k = blockIdx.x >> 3;
  const int cb = (blockIdx.x & 7) << 6;
  const int c = cb + lane;
  const int s0 = g * SG;

  float r[SG], w[SG], h[SG];
  params16(la, Bg, Cg, c, s0, r, w);

  if (USE_CARRY) {
    const float* crd = carry + (size_t)k * SC + s0 * CH_ + c;
#pragma unroll
    for (int i = 0; i < SG; ++i) h[i] = crd[i * CH_];
  } else {
#pragma unroll
    for (int i = 0; i < SG; ++i) h[i] = 0.0f;
  }

  const float* xp = x + (size_t)k * T * CH_ + c;
  float* yp = y + (size_t)k * T * CH_;

  for (int l = 0; l < T; l += 8) {
    float part[8];
#pragma unroll
    for (int jj = 0; jj < 8; ++jj) {
      const float xv = xp[(l + jj) * CH_];
      float a0 = 0, a1 = 0, a2 = 0, a3 = 0;
#pragma unroll
      for (int i = 0; i < SG; i += 4) {
        h[i]     = fmaf(r[i],     h[i],     xv);
        h[i + 1] = fmaf(r[i + 1], h[i + 1], xv);
        h[i + 2] = fmaf(r[i + 2], h[i + 2], xv);
        h[i + 3] = fmaf(r[i + 3], h[i + 3], xv);
        a0 = fmaf(w[i],     h[i],     a0);
        a1 = fmaf(w[i + 1], h[i + 1], a1);
        a2 = fmaf(w[i + 2], h[i + 2], a2);
        a3 = fmaf(w[i + 3], h[i + 3], a3);
      }
      part[jj] = (a0 + a1) + (a2 + a3);
    }

#pragma unroll
    for (int jj = 0; jj < 8; ++jj) lds[g][jj][lane] = part[jj];
    __syncthreads();

    // 512 (j,lane) outputs, 256 threads -> 2 each; 2-way bank alias is free.
#pragma unroll
    for (int p = 0; p < 2; ++p) {
      const int idx = (int)threadIdx.x + p * 256;
      const int jj = idx >> 6;
      const int ln = idx & 63;
      const float vv = (lds[0][jj][ln] + lds[1][jj][ln]) +
                       (lds[2][jj][ln] + lds[3][jj][ln]);
      yp[(size_t)(l + jj) * CH_ + cb + ln] = vv;
    }
    __syncthreads();
  }
}

}  // namespace

extern "C" void kernel_launch(void* const* d_in, const int* in_sizes, int n_in,
                              void* d_out, int out_size, void* d_ws, size_t ws_size,
                              hipStream_t stream) {
  const float* x = (const float*)d_in[0];
  const float* la = (const float*)d_in[1];
  const float* B = (const float*)d_in[2];
  const float* C = (const float*)d_in[3];
  float* y = (float*)d_out;
  float* carry = (float*)d_ws;

  const size_t need = (size_t)NC_ * SC * sizeof(float);  // 8 MB
  if (ws_size >= need) {
    k_local<T_><<<NC_ * 8, 256, 0, stream>>>(x, la, carry);
    k_comb<<<SC / 64, 256, 0, stream>>>(la, carry);
    k_scan<T_, true><<<NC_ * 8, 256, 0, stream>>>(x, la, B, C, carry, y);
  } else {
    // Degenerate single-dispatch path (no workspace): full-length serial scan.
    k_scan<L_, false><<<8, 256, 0, stream>>>(x, la, B, C, carry, y);
  }
}